// Round 1
// baseline (6186.258 us; speedup 1.0000x reference)
//
#include <hip/hip_runtime.h>
#include <math.h>

#define SELU_SCALE 1.0507009873554805f
#define SELU_ALPHA 1.6732632423543772f

__device__ __forceinline__ float selu_f(float x){
    return x > 0.f ? SELU_SCALE * x : SELU_SCALE * SELU_ALPHA * expm1f(x);
}

__device__ __forceinline__ float warp_sum(float v){
    #pragma unroll
    for(int o=32;o>0;o>>=1) v += __shfl_down(v,o,64);
    return v;
}
__device__ __forceinline__ float warp_max(float v){
    #pragma unroll
    for(int o=32;o>0;o>>=1) v = fmaxf(v,__shfl_down(v,o,64));
    return v;
}

// sum-reduce two values across the block. sred must have >=32 floats.
__device__ __forceinline__ void block_sum2(float &a, float &b, float* sred, int nw){
    int lane = threadIdx.x & 63, w = threadIdx.x >> 6;
    a = warp_sum(a); b = warp_sum(b);
    __syncthreads();
    if(lane==0){ sred[w]=a; sred[16+w]=b; }
    __syncthreads();
    if(w==0){
        float x = (lane<nw)? sred[lane] : 0.f;
        float y = (lane<nw)? sred[16+lane] : 0.f;
        x = warp_sum(x); y = warp_sum(y);
        if(lane==0){ sred[0]=x; sred[16]=y; }
    }
    __syncthreads();
    a = sred[0]; b = sred[16];
}

__device__ __forceinline__ float block_max_f(float v, float* sred, int nw){
    int lane = threadIdx.x & 63, w = threadIdx.x >> 6;
    v = warp_max(v);
    __syncthreads();
    if(lane==0) sred[w]=v;
    __syncthreads();
    if(w==0){
        float x = (lane<nw)? sred[lane] : -INFINITY;
        x = warp_max(x);
        if(lane==0) sred[0]=x;
    }
    __syncthreads();
    return sred[0];
}

// ---------------- Stage 1: conv1(1->32, 6x4 same) + SELU + GN(per-channel) + maxpool(2,4)
// block = (c, s); in: x[s][72][64]; out: buf1[s][32][36][16]
__global__ __launch_bounds__(256) void k_conv1(
    const float* __restrict__ x, const float* __restrict__ w, const float* __restrict__ bias,
    const float* __restrict__ g, const float* __restrict__ be, float* __restrict__ out)
{
    int c = blockIdx.x, s = blockIdx.y, tid = threadIdx.x;
    __shared__ float sin_[77*68];
    __shared__ float sout[72*64];
    __shared__ float sw[24];
    __shared__ float sred[32];
    if(tid < 24) sw[tid] = w[c*24 + tid];
    for(int i=tid;i<77*68;i+=256) sin_[i]=0.f;
    __syncthreads();
    const float* xs = x + (size_t)s*4608;
    for(int i=tid;i<4608;i+=256){ int r=i>>6, cc=i&63; sin_[(r+2)*68 + (cc+1)] = xs[i]; }
    __syncthreads();
    float b = bias[c];
    float lsum=0.f, lsq=0.f;
    for(int i=tid;i<4608;i+=256){
        int y=i>>6, xx=i&63;
        float acc=b;
        #pragma unroll
        for(int kh=0;kh<6;kh++){
            #pragma unroll
            for(int kw=0;kw<4;kw++)
                acc += sin_[(y+kh)*68 + xx+kw] * sw[kh*4+kw];
        }
        float v = selu_f(acc);
        sout[i]=v; lsum+=v; lsq+=v*v;
    }
    block_sum2(lsum,lsq,sred,4);
    float mean = lsum*(1.f/4608.f);
    float var  = lsq*(1.f/4608.f) - mean*mean;
    float inv  = rsqrtf(var + 1e-5f);
    float sc = g[c]*inv, sh = be[c] - mean*sc;
    float* o = out + ((size_t)s*32 + c)*576;
    for(int i=tid;i<576;i+=256){
        int py=i>>4, px=i&15;
        float m=-INFINITY;
        #pragma unroll
        for(int dy=0;dy<2;dy++)
            #pragma unroll
            for(int dx=0;dx<4;dx++){
                float v = sout[(py*2+dy)*64 + px*4+dx]*sc + sh;
                m = fmaxf(m,v);
            }
        o[i]=m;
    }
}

// ---------------- Stage 2: conv2(32->64, 6x4 same) + SELU + GN(2ch/group) + maxpool(3,4)
// block = (group gq of 2 out-ch, s); in: buf1[s][32][36][16]; out: buf2[s][64][12][4]
__global__ __launch_bounds__(576) void k_conv2(
    const float* __restrict__ in, const float* __restrict__ w, const float* __restrict__ bias,
    const float* __restrict__ g, const float* __restrict__ be, float* __restrict__ out)
{
    int gq = blockIdx.x, s = blockIdx.y, tid = threadIdx.x;
    __shared__ float sin_[41*20];
    __shared__ float sw[1536];       // 2 oc x 32 ic x 24
    __shared__ float snorm[1152];
    __shared__ float sred[32];
    for(int i=tid;i<1536;i+=576) sw[i] = w[gq*1536 + i];
    int y = tid/16, xx = tid%16;     // 576 = 36*16 exactly
    float acc0 = bias[2*gq], acc1 = bias[2*gq+1];
    const float* ibase = in + (size_t)s*32*576;
    for(int ic=0;ic<32;ic++){
        __syncthreads();
        for(int i=tid;i<820;i+=576){
            int r=i/20, cc=i%20;
            int ir=r-2, icc=cc-1;
            float v=0.f;
            if(ir>=0 && ir<36 && icc>=0 && icc<16) v = ibase[ic*576 + ir*16 + icc];
            sin_[i]=v;
        }
        __syncthreads();
        const float* w0 = sw + ic*24;
        const float* w1 = sw + (32+ic)*24;
        #pragma unroll
        for(int kh=0;kh<6;kh++){
            #pragma unroll
            for(int kw=0;kw<4;kw++){
                float iv = sin_[(y+kh)*20 + xx+kw];
                acc0 += iv * w0[kh*4+kw];
                acc1 += iv * w1[kh*4+kw];
            }
        }
    }
    float v0 = selu_f(acc0), v1 = selu_f(acc1);
    float lsum = v0+v1, lsq = v0*v0+v1*v1;
    block_sum2(lsum,lsq,sred,9);
    float mean = lsum*(1.f/1152.f), var = lsq*(1.f/1152.f) - mean*mean;
    float inv = rsqrtf(var + 1e-5f);
    float s0 = g[2*gq]*inv,   h0 = be[2*gq]   - mean*s0;
    float s1 = g[2*gq+1]*inv, h1 = be[2*gq+1] - mean*s1;
    snorm[tid]     = v0*s0 + h0;
    snorm[576+tid] = v1*s1 + h1;
    __syncthreads();
    if(tid < 96){
        int j=tid/48, p=tid%48, py=p>>2, px=p&3;
        float m=-INFINITY;
        #pragma unroll
        for(int dy=0;dy<3;dy++)
            #pragma unroll
            for(int dx=0;dx<4;dx++)
                m = fmaxf(m, snorm[j*576 + (py*3+dy)*16 + px*4+dx]);
        out[((size_t)s*64 + 2*gq + j)*48 + p] = m;
    }
}

// ---------------- Stage 3: conv3(64->128, 6x4 same) + SELU + GN(4ch/group) + maxpool(3,2)
// block = (group gq of 4 out-ch, s); in: buf2[s][64][12][4]; out: e0[s][1024] (c*8+y*2+x)
__global__ __launch_bounds__(192) void k_conv3(
    const float* __restrict__ in, const float* __restrict__ w, const float* __restrict__ bias,
    const float* __restrict__ g, const float* __restrict__ be, float* __restrict__ e0)
{
    int gq = blockIdx.x, s = blockIdx.y, tid = threadIdx.x;
    __shared__ float sin_[64*136];   // 64 ch x 17 rows x stride 8 (7 cols)
    __shared__ float sw[6144];       // 4 oc x 64 ic x 24
    __shared__ float snorm[192];
    __shared__ float sred[32];
    for(int i=tid;i<6144;i+=192) sw[i] = w[gq*6144 + i];
    const float* ibase = in + (size_t)s*64*48;
    for(int i=tid;i<64*136;i+=192){
        int ic=i/136, rem=i%136, r=rem>>3, cc=rem&7;
        int ir=r-2, icc=cc-1;
        float v=0.f;
        if(ir>=0 && ir<12 && icc>=0 && icc<4 && cc<7) v = ibase[ic*48 + ir*4 + icc];
        sin_[i]=v;
    }
    __syncthreads();
    int oc = tid/48, p = tid%48, y = p>>2, xx = p&3;
    float acc = bias[4*gq+oc];
    for(int ic=0;ic<64;ic++){
        const float* sb = sin_ + ic*136;
        const float* wb = sw + (oc*64+ic)*24;
        #pragma unroll
        for(int kh=0;kh<6;kh++){
            #pragma unroll
            for(int kw=0;kw<4;kw++)
                acc += sb[(y+kh)*8 + xx+kw] * wb[kh*4+kw];
        }
    }
    float v = selu_f(acc);
    float lsum=v, lsq=v*v;
    block_sum2(lsum,lsq,sred,3);
    float mean = lsum*(1.f/192.f), var = lsq*(1.f/192.f) - mean*mean;
    float inv = rsqrtf(var + 1e-5f);
    float sc = g[4*gq+oc]*inv, sh = be[4*gq+oc] - mean*sc;
    snorm[tid] = v*sc + sh;
    __syncthreads();
    if(tid < 32){
        int oc2 = tid/8, pp = tid%8, py = pp>>1, px = pp&1;
        float m=-INFINITY;
        #pragma unroll
        for(int dy=0;dy<3;dy++)
            #pragma unroll
            for(int dx=0;dx<2;dx++)
                m = fmaxf(m, snorm[oc2*48 + (py*3+dy)*4 + px*2+dx]);
        e0[(size_t)s*1024 + (4*gq+oc2)*8 + pp] = m;
    }
}

// ---------------- transpose helper: dst[c*R+r] = src[r*C+c]
__global__ void k_transpose(const float* __restrict__ src, float* __restrict__ dst, int R, int C){
    int idx = blockIdx.x*256 + threadIdx.x;
    if(idx < R*C){ int r = idx / C, c = idx % C; dst[c*R + r] = src[idx]; }
}

// ---------------- FC1 + SELU + row l2norm. wt is [1024][128]
__global__ __launch_bounds__(128) void k_fc1(
    const float* __restrict__ e0, const float* __restrict__ wt,
    const float* __restrict__ bias, float* __restrict__ e)
{
    int s = blockIdx.x, j = threadIdx.x;
    __shared__ float se[1024];
    __shared__ float sred[32];
    for(int i=j;i<1024;i+=128) se[i] = e0[(size_t)s*1024+i];
    __syncthreads();
    float acc = bias[j];
    for(int i=0;i<1024;i++) acc += se[i]*wt[i*128+j];
    float v = selu_f(acc);
    float a = v*v, b = 0.f;
    block_sum2(a,b,sred,2);
    float den = fmaxf(sqrtf(a), 1e-12f);
    e[(size_t)s*128+j] = v/den;
}

// ---------------- q,k,v projections + SELU; k gets positional encoding added
__global__ __launch_bounds__(128) void k_qkv(
    const float* __restrict__ e,
    const float* __restrict__ wqt, const float* __restrict__ bq,
    const float* __restrict__ wkt, const float* __restrict__ bk,
    const float* __restrict__ wvt, const float* __restrict__ bv,
    float* __restrict__ q, float* __restrict__ kp, float* __restrict__ v)
{
    int s = blockIdx.x, j = threadIdx.x;
    __shared__ float se[128];
    se[j] = e[(size_t)s*128+j];
    __syncthreads();
    float aq = bq[j], ak = bk[j], av = bv[j];
    for(int i=0;i<128;i++){
        float f = se[i];
        aq += f*wqt[i*128+j];
        ak += f*wkt[i*128+j];
        av += f*wvt[i*128+j];
    }
    aq = selu_f(aq); ak = selu_f(ak); av = selu_f(av);
    int i2 = j & ~1;
    float div = expf(-(float)i2 * 0.07195578412155481f); // ln(10000)/128
    float ang = (float)s * div;
    float pe = (j & 1) ? cosf(ang) : sinf(ang);
    q[(size_t)s*128+j]  = aq;
    kp[(size_t)s*128+j] = ak + pe;
    v[(size_t)s*128+j]  = av;
}

// ---------------- scores + softmax row
__global__ __launch_bounds__(256) void k_attn(
    const float* __restrict__ q, const float* __restrict__ kp, float* __restrict__ attn)
{
    int s = blockIdx.x, tid = threadIdx.x;
    __shared__ float sq_[128];
    __shared__ float sred[32];
    if(tid < 128) sq_[tid] = q[(size_t)s*128+tid];
    __syncthreads();
    float val[4];
    const float4* qr = (const float4*)sq_;
    #pragma unroll
    for(int k2=0;k2<4;k2++){
        int t = tid + k2*256;
        const float4* kr = (const float4*)(kp + (size_t)t*128);
        float acc=0.f;
        #pragma unroll 8
        for(int i=0;i<32;i++){
            float4 a=qr[i], b=kr[i];
            acc += a.x*b.x + a.y*b.y + a.z*b.z + a.w*b.w;
        }
        val[k2] = acc * 0.08838834764831845f; // 1/sqrt(128)
    }
    float m = fmaxf(fmaxf(val[0],val[1]), fmaxf(val[2],val[3]));
    m = block_max_f(m,sred,4);
    float lsum=0.f, dummy=0.f;
    #pragma unroll
    for(int k2=0;k2<4;k2++){ val[k2]=expf(val[k2]-m); lsum+=val[k2]; }
    block_sum2(lsum,dummy,sred,4);
    float invs = 1.f/lsum;
    #pragma unroll
    for(int k2=0;k2<4;k2++) attn[(size_t)s*1024 + tid + k2*256] = val[k2]*invs;
}

// ---------------- av = attn @ v
__global__ __launch_bounds__(128) void k_av(
    const float* __restrict__ attn, const float* __restrict__ v, float* __restrict__ av)
{
    int s = blockIdx.x, j = threadIdx.x;
    __shared__ float sa[1024];
    for(int i=j;i<1024;i+=128) sa[i] = attn[(size_t)s*1024+i];
    __syncthreads();
    float acc=0.f;
    for(int t=0;t<1024;t++) acc += sa[t]*v[t*128+j];
    av[(size_t)s*128+j] = acc;
}

// ---------------- column l2norm (axis=0) twice: out = l2(av)+e; ea = l2(out). single block.
__global__ __launch_bounds__(128) void k_colnorm(
    float* __restrict__ av, const float* __restrict__ e, float* __restrict__ ea)
{
    int j = threadIdx.x;
    float s1=0.f;
    for(int s=0;s<1024;s++){ float a=av[s*128+j]; s1+=a*a; }
    float n1 = fmaxf(sqrtf(s1), 1e-12f);
    float s2=0.f;
    for(int s=0;s<1024;s++){
        float o = av[s*128+j]/n1 + e[s*128+j];
        av[s*128+j] = o;
        s2 += o*o;
    }
    float n2 = fmaxf(sqrtf(s2), 1e-12f);
    for(int s=0;s<1024;s++) ea[s*128+j] = av[s*128+j]/n2;
}

// ---------------- sq[s] = ||ea[s,:]||^2
__global__ __launch_bounds__(128) void k_sq(const float* __restrict__ ea, float* __restrict__ sq){
    int s = blockIdx.x, j = threadIdx.x;
    __shared__ float sred[32];
    float v = ea[(size_t)s*128+j];
    float a=v*v, b=0.f;
    block_sum2(a,b,sred,2);
    if(j==0) sq[s]=a;
}

// ---------------- pairwise d2 + global max(d2) via atomic bits-max
__global__ __launch_bounds__(256) void k_gram(
    const float* __restrict__ ea, const float* __restrict__ sq,
    float* __restrict__ d2, unsigned int* __restrict__ maxbits)
{
    int j0 = blockIdx.x*32, i0 = blockIdx.y*32, tid = threadIdx.x;
    __shared__ float sa[32*128];
    __shared__ float sb[32*128];
    __shared__ float sred[32];
    for(int idx=tid;idx<4096;idx+=256){
        sa[idx] = ea[(size_t)i0*128 + idx];
        sb[idx] = ea[(size_t)j0*128 + idx];
    }
    __syncthreads();
    float lm = 0.f;
    #pragma unroll
    for(int k2=0;k2<4;k2++){
        int p = tid + k2*256;
        int li = p>>5, lj = p&31;
        const float4* A = (const float4*)(sa + li*128);
        const float4* B = (const float4*)(sb + lj*128);
        float acc=0.f;
        #pragma unroll 8
        for(int i=0;i<32;i++){
            float4 a=A[i], b=B[i];
            acc += a.x*b.x + a.y*b.y + a.z*b.z + a.w*b.w;
        }
        float dd = fmaxf(sq[i0+li] + sq[j0+lj] - 2.f*acc, 0.f);
        d2[(size_t)(i0+li)*1024 + j0+lj] = dd;
        lm = fmaxf(lm, dd);
    }
    lm = block_max_f(lm,sred,4);
    if(tid==0) atomicMax(maxbits, __float_as_uint(lm));
}

// ---------------- out = 1 - sqrt(d2+eps)/maxd
__global__ __launch_bounds__(256) void k_final(
    const float* __restrict__ d2, const unsigned int* __restrict__ maxbits, float* __restrict__ out)
{
    int idx = blockIdx.x*256 + threadIdx.x;
    float md = sqrtf(__uint_as_float(*maxbits) + 1e-12f);
    out[idx] = 1.f - sqrtf(d2[idx] + 1e-12f)/md;
}

extern "C" void kernel_launch(void* const* d_in, const int* in_sizes, int n_in,
                              void* d_out, int out_size, void* d_ws, size_t ws_size,
                              hipStream_t stream)
{
    const float* x   = (const float*)d_in[0];
    const float* c1w = (const float*)d_in[1];  const float* c1b = (const float*)d_in[2];
    const float* g1g = (const float*)d_in[3];  const float* g1b = (const float*)d_in[4];
    const float* c2w = (const float*)d_in[5];  const float* c2b = (const float*)d_in[6];
    const float* g2g = (const float*)d_in[7];  const float* g2b = (const float*)d_in[8];
    const float* c3w = (const float*)d_in[9];  const float* c3b = (const float*)d_in[10];
    const float* g3g = (const float*)d_in[11]; const float* g3b = (const float*)d_in[12];
    const float* f1w = (const float*)d_in[13]; const float* f1b = (const float*)d_in[14];
    const float* wq  = (const float*)d_in[15]; const float* bq  = (const float*)d_in[16];
    const float* wk  = (const float*)d_in[17]; const float* bk  = (const float*)d_in[18];
    const float* wv  = (const float*)d_in[19]; const float* bv  = (const float*)d_in[20];

    float* W = (float*)d_ws;
    // Region A (aliases buf1, which is dead by the time these are written):
    float* e0   = W;                 // 1,048,576
    float* attn = W + 1048576;       // 1,048,576
    float* avb  = W + 2097152;       //   131,072
    float* eab  = W + 2228224;       //   131,072
    float* d2b  = W + 2359296;       // 1,048,576
    float* buf1 = W;                 // 18,874,368 (stage1 out, dead after k_conv2)
    float* buf2 = W + 18874368;      //  3,145,728 (stage2 out)
    float* wt   = W + 22020096;      //   131,072 (fc1_w transposed)
    float* wqt  = W + 22151168;      //    16,384
    float* wkt  = W + 22167552;      //    16,384
    float* wvt  = W + 22183936;      //    16,384
    float* eb   = W + 22200320;      //   131,072
    float* qb   = W + 22331392;      //   131,072
    float* kpb  = W + 22462464;      //   131,072
    float* vb   = W + 22593536;      //   131,072
    float* sqb  = W + 22724608;      //     1,024
    unsigned int* maxb = (unsigned int*)(W + 22725632);

    k_transpose<<<512,256,0,stream>>>(f1w, wt, 128, 1024);
    k_transpose<<<64,256,0,stream>>>(wq, wqt, 128, 128);
    k_transpose<<<64,256,0,stream>>>(wk, wkt, 128, 128);
    k_transpose<<<64,256,0,stream>>>(wv, wvt, 128, 128);

    k_conv1<<<dim3(32,1024),256,0,stream>>>(x,  c1w,c1b,g1g,g1b, buf1);
    k_conv2<<<dim3(32,1024),576,0,stream>>>(buf1,c2w,c2b,g2g,g2b, buf2);
    k_conv3<<<dim3(32,1024),192,0,stream>>>(buf2,c3w,c3b,g3g,g3b, e0);

    k_fc1<<<1024,128,0,stream>>>(e0, wt, f1b, eb);
    k_qkv<<<1024,128,0,stream>>>(eb, wqt,bq, wkt,bk, wvt,bv, qb,kpb,vb);
    k_attn<<<1024,256,0,stream>>>(qb, kpb, attn);
    k_av<<<1024,128,0,stream>>>(attn, vb, avb);

    hipMemsetAsync(maxb, 0, 4, stream);
    k_colnorm<<<1,128,0,stream>>>(avb, eb, eab);
    k_sq<<<1024,128,0,stream>>>(eab, sqb);
    k_gram<<<dim3(32,32),256,0,stream>>>(eab, sqb, d2b, maxb);
    k_final<<<4096,256,0,stream>>>(d2b, maxb, (float*)d_out);
}

// Round 2
// 2321.354 us; speedup vs baseline: 2.6649x; 2.6649x over previous
//
#include <hip/hip_runtime.h>
#include <math.h>

#define SELU_SCALE 1.0507009873554805f
#define SELU_ALPHA 1.6732632423543772f

__device__ __forceinline__ float selu_f(float x){
    return x > 0.f ? SELU_SCALE * x : SELU_SCALE * SELU_ALPHA * expm1f(x);
}

__device__ __forceinline__ float warp_sum(float v){
    #pragma unroll
    for(int o=32;o>0;o>>=1) v += __shfl_down(v,o,64);
    return v;
}
__device__ __forceinline__ float warp_max(float v){
    #pragma unroll
    for(int o=32;o>0;o>>=1) v = fmaxf(v,__shfl_down(v,o,64));
    return v;
}

__device__ __forceinline__ void block_sum2(float &a, float &b, float* sred, int nw){
    int lane = threadIdx.x & 63, w = threadIdx.x >> 6;
    a = warp_sum(a); b = warp_sum(b);
    __syncthreads();
    if(lane==0){ sred[w]=a; sred[16+w]=b; }
    __syncthreads();
    if(w==0){
        float x = (lane<nw)? sred[lane] : 0.f;
        float y = (lane<nw)? sred[16+lane] : 0.f;
        x = warp_sum(x); y = warp_sum(y);
        if(lane==0){ sred[0]=x; sred[16]=y; }
    }
    __syncthreads();
    a = sred[0]; b = sred[16];
}

__device__ __forceinline__ float block_max_f(float v, float* sred, int nw){
    int lane = threadIdx.x & 63, w = threadIdx.x >> 6;
    v = warp_max(v);
    __syncthreads();
    if(lane==0) sred[w]=v;
    __syncthreads();
    if(w==0){
        float x = (lane<nw)? sred[lane] : -INFINITY;
        x = warp_max(x);
        if(lane==0) sred[0]=x;
    }
    __syncthreads();
    return sred[0];
}

// ============ Stage 1: conv1(1->32) + SELU + GN(1ch/grp) + maxpool(2,4)
// grid (4 ocq, 1024 s), block 256. lane = x (0..63), wave = yg (0..3).
// thread computes 8 oc x 18-row column strip.
__global__ __launch_bounds__(256,2) void k_conv1(
    const float* __restrict__ x, const float* __restrict__ w, const float* __restrict__ bias,
    const float* __restrict__ g, const float* __restrict__ be, float* __restrict__ out)
{
    int ocq = blockIdx.x, s = blockIdx.y, tid = threadIdx.x;
    int x_ = tid & 63, yg = tid >> 6;
    __shared__ float sin_[77*68];
    __shared__ float sw[24*8];          // [khw][8oc]
    __shared__ float sred[4][8][2];
    if(tid < 192){ int khw = tid/8, o = tid%8; sw[tid] = w[(ocq*8+o)*24 + khw]; }
    for(int i=tid;i<77*68;i+=256) sin_[i]=0.f;
    __syncthreads();
    const float* xs = x + (size_t)s*4608;
    for(int i=tid;i<4608;i+=256){ int r=i>>6, cc=i&63; sin_[(r+2)*68 + (cc+1)] = xs[i]; }
    __syncthreads();

    float acc[8][18];
    #pragma unroll
    for(int o=0;o<8;o++){
        float bb = bias[ocq*8+o];
        #pragma unroll
        for(int p=0;p<18;p++) acc[o][p]=bb;
    }
    int y0 = yg*18;
    for(int kw=0;kw<4;kw++){
        float col[23];
        #pragma unroll
        for(int r=0;r<23;r++) col[r] = sin_[(y0+r)*68 + x_ + kw];
        #pragma unroll
        for(int kh=0;kh<6;kh++){
            const float4* wp = (const float4*)(sw + (kh*4+kw)*8);
            float4 wa = wp[0], wb = wp[1];
            float wv[8] = {wa.x,wa.y,wa.z,wa.w,wb.x,wb.y,wb.z,wb.w};
            #pragma unroll
            for(int p=0;p<18;p++){
                float v = col[p+kh];
                #pragma unroll
                for(int o=0;o<8;o++) acc[o][p] = fmaf(v, wv[o], acc[o][p]);
            }
        }
    }
    // SELU + per-oc stats over 4608 px
    float sum[8], sq[8];
    #pragma unroll
    for(int o=0;o<8;o++){
        float a=0.f,b=0.f;
        #pragma unroll
        for(int p=0;p<18;p++){
            float v = selu_f(acc[o][p]); acc[o][p]=v;
            a += v; b += v*v;
        }
        #pragma unroll
        for(int off=1;off<64;off<<=1){ a += __shfl_xor(a,off); b += __shfl_xor(b,off); }
        sum[o]=a; sq[o]=b;
    }
    if(x_ < 8){ sred[yg][x_][0]=sum[x_]; sred[yg][x_][1]=sq[x_]; }
    __syncthreads();
    float* o_ = out + ((size_t)s*32 + ocq*8)*576;
    #pragma unroll
    for(int o=0;o<8;o++){
        float ts = sred[0][o][0]+sred[1][o][0]+sred[2][o][0]+sred[3][o][0];
        float tq = sred[0][o][1]+sred[1][o][1]+sred[2][o][1]+sred[3][o][1];
        float mean = ts*(1.f/4608.f);
        float var  = tq*(1.f/4608.f) - mean*mean;
        float inv  = rsqrtf(var + 1e-5f);
        float sc = g[ocq*8+o]*inv, sh = be[ocq*8+o] - mean*sc;
        #pragma unroll
        for(int p=0;p<18;p++) acc[o][p] = acc[o][p]*sc + sh;
        // pool 2x4: rows in-thread, cols across 4 lanes
        #pragma unroll
        for(int py=0;py<9;py++){
            float m = fmaxf(acc[o][2*py],acc[o][2*py+1]);
            m = fmaxf(m, __shfl_xor(m,1));
            m = fmaxf(m, __shfl_xor(m,2));
            if((x_&3)==0) o_[o*576 + (yg*9+py)*16 + (x_>>2)] = m;
        }
    }
}

// ============ Stage 2: conv2(32->64) + SELU + GN(2ch/grp) + maxpool(3,4)
// grid (1024 s), block 256: t = ocsub*32 + yg*16 + x. thread: 8 oc x 18-row strip.
__global__ __launch_bounds__(256,2) void k_conv2(
    const float* __restrict__ in, const float* __restrict__ w2, const float* __restrict__ bias,
    const float* __restrict__ g, const float* __restrict__ be, float* __restrict__ out)
{
    int s = blockIdx.x, tid = threadIdx.x;
    int ocsub = tid >> 5, yg = (tid >> 4) & 1, x_ = tid & 15;
    __shared__ float sinc[4*820];       // [icl][41*20]
    __shared__ float swc[4*24*64];      // [icl][khw][64oc]
    const float* ibase = in + (size_t)s*18432;
    float acc[8][18];
    #pragma unroll
    for(int o=0;o<8;o++){
        float bb = bias[ocsub*8+o];
        #pragma unroll
        for(int p=0;p<18;p++) acc[o][p]=bb;
    }
    int y0 = yg*18;
    for(int ic0=0; ic0<32; ic0+=4){
        __syncthreads();
        for(int i=tid;i<3280;i+=256){
            int icl = i/820, rem = i - icl*820;
            int r = rem/20, cc = rem - r*20;
            int ir = r-2, icc = cc-1;
            float v = 0.f;
            if(ir>=0 && ir<36 && icc>=0 && icc<16) v = ibase[(ic0+icl)*576 + ir*16 + icc];
            sinc[i]=v;
        }
        for(int i=tid;i<6144;i+=256){
            int icl = i/1536, rem = i - icl*1536;
            int khw = rem>>6, oc = rem&63;
            swc[i] = w2[(size_t)oc*768 + (ic0+icl)*24 + khw];
        }
        __syncthreads();
        for(int icl=0; icl<4; icl++){
            for(int kw=0;kw<4;kw++){
                float col[23];
                #pragma unroll
                for(int r=0;r<23;r++) col[r] = sinc[icl*820 + (y0+r)*20 + x_ + kw];
                #pragma unroll
                for(int kh=0;kh<6;kh++){
                    const float4* wp = (const float4*)(swc + (icl*24 + kh*4+kw)*64 + ocsub*8);
                    float4 wa = wp[0], wb = wp[1];
                    float wv[8] = {wa.x,wa.y,wa.z,wa.w,wb.x,wb.y,wb.z,wb.w};
                    #pragma unroll
                    for(int p=0;p<18;p++){
                        float v = col[p+kh];
                        #pragma unroll
                        for(int o=0;o<8;o++) acc[o][p] = fmaf(v, wv[o], acc[o][p]);
                    }
                }
            }
        }
    }
    // SELU + GN stats: group = 2 consecutive oc, over 576 px (32 strip-threads share group)
    float gs[4], gq[4];
    #pragma unroll
    for(int gl=0; gl<4; gl++){
        float a=0.f,b=0.f;
        #pragma unroll
        for(int oo=0;oo<2;oo++){
            int o = gl*2+oo;
            #pragma unroll
            for(int p=0;p<18;p++){
                float v = selu_f(acc[o][p]); acc[o][p]=v;
                a += v; b += v*v;
            }
        }
        #pragma unroll
        for(int off=1;off<32;off<<=1){ a += __shfl_xor(a,off); b += __shfl_xor(b,off); }
        gs[gl]=a; gq[gl]=b;
    }
    float* ob = out + ((size_t)s*64 + ocsub*8)*48;
    #pragma unroll
    for(int o=0;o<8;o++){
        int gl = o>>1;
        float mean = gs[gl]*(1.f/1152.f);
        float var  = gq[gl]*(1.f/1152.f) - mean*mean;
        float inv  = rsqrtf(var + 1e-5f);
        int oc = ocsub*8+o;
        float sc = g[oc]*inv, sh = be[oc] - mean*sc;
        #pragma unroll
        for(int p=0;p<18;p++) acc[o][p] = acc[o][p]*sc + sh;
        // pool 3x4: 3 rows in-thread, 4 cols across lanes
        #pragma unroll
        for(int py=0;py<6;py++){
            float m = fmaxf(fmaxf(acc[o][3*py],acc[o][3*py+1]),acc[o][3*py+2]);
            m = fmaxf(m, __shfl_xor(m,1));
            m = fmaxf(m, __shfl_xor(m,2));
            if((x_&3)==0) ob[o*48 + (yg*6+py)*4 + (x_>>2)] = m;
        }
    }
}

// ============ Stage 3: conv3(64->128) + SELU + GN(4ch/grp) + maxpool(3,2)
// grid (256 sq of 4 samples), block 256: t = sL*64 + ocsub*4 + x. thread: 8 oc x 12-row col.
__global__ __launch_bounds__(256,2) void k_conv3(
    const float* __restrict__ in, const float* __restrict__ w3, const float* __restrict__ bias,
    const float* __restrict__ g, const float* __restrict__ be, float* __restrict__ e0)
{
    int sq = blockIdx.x, tid = threadIdx.x;
    int sL = tid >> 6, ocsub = (tid >> 2) & 15, x_ = tid & 3;
    __shared__ float sinb[4*64*48];     // [sL][ic][12*4]
    __shared__ float swc[2*24*128];     // [icl][khw][128oc]
    for(int i=tid;i<12288;i+=256) sinb[i] = in[(size_t)sq*12288 + i];
    float acc[8][12];
    #pragma unroll
    for(int o=0;o<8;o++){
        float bb = bias[ocsub*8+o];
        #pragma unroll
        for(int p=0;p<12;p++) acc[o][p]=bb;
    }
    const float* sbase = sinb + sL*64*48;
    for(int ic0=0; ic0<64; ic0+=2){
        __syncthreads();
        for(int i=tid;i<6144;i+=256){
            int icl = i/3072, rem = i - icl*3072;
            int khw = rem>>7, oc = rem&127;
            swc[i] = w3[(size_t)oc*1536 + (ic0+icl)*24 + khw];
        }
        __syncthreads();
        for(int icl=0; icl<2; icl++){
            const float* ib = sbase + (ic0+icl)*48;
            for(int kw=0;kw<4;kw++){
                int xx = x_ + kw - 1;
                bool xv = (xx>=0 && xx<4);
                float col[17];
                #pragma unroll
                for(int r=0;r<17;r++){
                    int ir = r-2;
                    bool vld = xv && ir>=0 && ir<12;
                    int off = vld ? (ir*4+xx) : 0;
                    float v = ib[off];
                    col[r] = vld ? v : 0.f;
                }
                #pragma unroll
                for(int kh=0;kh<6;kh++){
                    const float4* wp = (const float4*)(swc + (icl*24 + kh*4+kw)*128 + ocsub*8);
                    float4 wa = wp[0], wb = wp[1];
                    float wv[8] = {wa.x,wa.y,wa.z,wa.w,wb.x,wb.y,wb.z,wb.w};
                    #pragma unroll
                    for(int p=0;p<12;p++){
                        float v = col[p+kh];
                        #pragma unroll
                        for(int o=0;o<8;o++) acc[o][p] = fmaf(v, wv[o], acc[o][p]);
                    }
                }
            }
        }
    }
    // SELU + GN stats: group = 4 consecutive oc over 48 px (4 x-lanes share group)
    float gs[2], gq[2];
    #pragma unroll
    for(int gl=0; gl<2; gl++){
        float a=0.f,b=0.f;
        #pragma unroll
        for(int oo=0;oo<4;oo++){
            int o = gl*4+oo;
            #pragma unroll
            for(int p=0;p<12;p++){
                float v = selu_f(acc[o][p]); acc[o][p]=v;
                a += v; b += v*v;
            }
        }
        a += __shfl_xor(a,1); a += __shfl_xor(a,2);
        b += __shfl_xor(b,1); b += __shfl_xor(b,2);
        gs[gl]=a; gq[gl]=b;
    }
    float* eb_ = e0 + (size_t)(sq*4+sL)*1024 + ocsub*8*8;
    #pragma unroll
    for(int o=0;o<8;o++){
        int gl = o>>2;
        float mean = gs[gl]*(1.f/192.f);
        float var  = gq[gl]*(1.f/192.f) - mean*mean;
        float inv  = rsqrtf(var + 1e-5f);
        int oc = ocsub*8+o;
        float sc = g[oc]*inv, sh = be[oc] - mean*sc;
        #pragma unroll
        for(int p=0;p<12;p++) acc[o][p] = acc[o][p]*sc + sh;
        // pool 3x2: 3 rows in-thread, 2 cols across lanes
        #pragma unroll
        for(int py=0;py<4;py++){
            float m = fmaxf(fmaxf(acc[o][3*py],acc[o][3*py+1]),acc[o][3*py+2]);
            m = fmaxf(m, __shfl_xor(m,1));
            if((x_&1)==0) eb_[o*8 + py*2 + (x_>>1)] = m;
        }
    }
}

// ---------------- transpose helper: dst[c*R+r] = src[r*C+c]
__global__ void k_transpose(const float* __restrict__ src, float* __restrict__ dst, int R, int C){
    int idx = blockIdx.x*256 + threadIdx.x;
    if(idx < R*C){ int r = idx / C, c = idx % C; dst[c*R + r] = src[idx]; }
}

// ---------------- FC1 + SELU + row l2norm. wt is [1024][128]
__global__ __launch_bounds__(128) void k_fc1(
    const float* __restrict__ e0, const float* __restrict__ wt,
    const float* __restrict__ bias, float* __restrict__ e)
{
    int s = blockIdx.x, j = threadIdx.x;
    __shared__ float se[1024];
    __shared__ float sred[32];
    for(int i=j;i<1024;i+=128) se[i] = e0[(size_t)s*1024+i];
    __syncthreads();
    float acc = bias[j];
    for(int i=0;i<1024;i++) acc += se[i]*wt[i*128+j];
    float v = selu_f(acc);
    float a = v*v, b = 0.f;
    block_sum2(a,b,sred,2);
    float den = fmaxf(sqrtf(a), 1e-12f);
    e[(size_t)s*128+j] = v/den;
}

// ---------------- q,k,v projections + SELU; k gets positional encoding added
__global__ __launch_bounds__(128) void k_qkv(
    const float* __restrict__ e,
    const float* __restrict__ wqt, const float* __restrict__ bq,
    const float* __restrict__ wkt, const float* __restrict__ bk,
    const float* __restrict__ wvt, const float* __restrict__ bv,
    float* __restrict__ q, float* __restrict__ kp, float* __restrict__ v)
{
    int s = blockIdx.x, j = threadIdx.x;
    __shared__ float se[128];
    se[j] = e[(size_t)s*128+j];
    __syncthreads();
    float aq = bq[j], ak = bk[j], av = bv[j];
    for(int i=0;i<128;i++){
        float f = se[i];
        aq += f*wqt[i*128+j];
        ak += f*wkt[i*128+j];
        av += f*wvt[i*128+j];
    }
    aq = selu_f(aq); ak = selu_f(ak); av = selu_f(av);
    int i2 = j & ~1;
    float div = expf(-(float)i2 * 0.07195578412155481f); // ln(10000)/128
    float ang = (float)s * div;
    float pe = (j & 1) ? cosf(ang) : sinf(ang);
    q[(size_t)s*128+j]  = aq;
    kp[(size_t)s*128+j] = ak + pe;
    v[(size_t)s*128+j]  = av;
}

// ---------------- scores + softmax row
__global__ __launch_bounds__(256) void k_attn(
    const float* __restrict__ q, const float* __restrict__ kp, float* __restrict__ attn)
{
    int s = blockIdx.x, tid = threadIdx.x;
    __shared__ float sq_[128];
    __shared__ float sred[32];
    if(tid < 128) sq_[tid] = q[(size_t)s*128+tid];
    __syncthreads();
    float val[4];
    const float4* qr = (const float4*)sq_;
    #pragma unroll
    for(int k2=0;k2<4;k2++){
        int t = tid + k2*256;
        const float4* kr = (const float4*)(kp + (size_t)t*128);
        float acc=0.f;
        #pragma unroll 8
        for(int i=0;i<32;i++){
            float4 a=qr[i], b=kr[i];
            acc += a.x*b.x + a.y*b.y + a.z*b.z + a.w*b.w;
        }
        val[k2] = acc * 0.08838834764831845f; // 1/sqrt(128)
    }
    float m = fmaxf(fmaxf(val[0],val[1]), fmaxf(val[2],val[3]));
    m = block_max_f(m,sred,4);
    float lsum=0.f, dummy=0.f;
    #pragma unroll
    for(int k2=0;k2<4;k2++){ val[k2]=expf(val[k2]-m); lsum+=val[k2]; }
    block_sum2(lsum,dummy,sred,4);
    float invs = 1.f/lsum;
    #pragma unroll
    for(int k2=0;k2<4;k2++) attn[(size_t)s*1024 + tid + k2*256] = val[k2]*invs;
}

// ---------------- av = attn @ v
__global__ __launch_bounds__(128) void k_av(
    const float* __restrict__ attn, const float* __restrict__ v, float* __restrict__ av)
{
    int s = blockIdx.x, j = threadIdx.x;
    __shared__ float sa[1024];
    for(int i=j;i<1024;i+=128) sa[i] = attn[(size_t)s*1024+i];
    __syncthreads();
    float acc=0.f;
    for(int t=0;t<1024;t++) acc += sa[t]*v[t*128+j];
    av[(size_t)s*128+j] = acc;
}

// ---------------- column pipeline: n1 = ||av[:,j]||, out = av/n1 + e, n2, ea = out/n2
// grid 128 (one column), block 256
__global__ __launch_bounds__(256) void k_colpipe(
    const float* __restrict__ av, const float* __restrict__ e, float* __restrict__ ea)
{
    int j = blockIdx.x, t = threadIdx.x;
    __shared__ float sred[4];
    float v[4];
    float ss = 0.f;
    #pragma unroll
    for(int k=0;k<4;k++){
        v[k] = av[(size_t)(t + 256*k)*128 + j];
        ss += v[k]*v[k];
    }
    #pragma unroll
    for(int off=1;off<64;off<<=1) ss += __shfl_xor(ss,off);
    int lane = t & 63, w = t >> 6;
    if(lane==0) sred[w]=ss;
    __syncthreads();
    float n1 = fmaxf(sqrtf(sred[0]+sred[1]+sred[2]+sred[3]), 1e-12f);
    __syncthreads();
    float ss2 = 0.f;
    #pragma unroll
    for(int k=0;k<4;k++){
        float o = v[k]/n1 + e[(size_t)(t + 256*k)*128 + j];
        v[k] = o;
        ss2 += o*o;
    }
    #pragma unroll
    for(int off=1;off<64;off<<=1) ss2 += __shfl_xor(ss2,off);
    if(lane==0) sred[w]=ss2;
    __syncthreads();
    float n2 = fmaxf(sqrtf(sred[0]+sred[1]+sred[2]+sred[3]), 1e-12f);
    #pragma unroll
    for(int k=0;k<4;k++) ea[(size_t)(t + 256*k)*128 + j] = v[k]/n2;
}

// ---------------- sq[s] = ||ea[s,:]||^2
__global__ __launch_bounds__(128) void k_sq(const float* __restrict__ ea, float* __restrict__ sq){
    int s = blockIdx.x, j = threadIdx.x;
    __shared__ float sred[32];
    float v = ea[(size_t)s*128+j];
    float a=v*v, b=0.f;
    block_sum2(a,b,sred,2);
    if(j==0) sq[s]=a;
}

// ---------------- pairwise d2 + global max(d2) via atomic bits-max
__global__ __launch_bounds__(256) void k_gram(
    const float* __restrict__ ea, const float* __restrict__ sq,
    float* __restrict__ d2, unsigned int* __restrict__ maxbits)
{
    int j0 = blockIdx.x*32, i0 = blockIdx.y*32, tid = threadIdx.x;
    __shared__ float sa[32*128];
    __shared__ float sb[32*128];
    __shared__ float sred[32];
    for(int idx=tid;idx<4096;idx+=256){
        sa[idx] = ea[(size_t)i0*128 + idx];
        sb[idx] = ea[(size_t)j0*128 + idx];
    }
    __syncthreads();
    float lm = 0.f;
    #pragma unroll
    for(int k2=0;k2<4;k2++){
        int p = tid + k2*256;
        int li = p>>5, lj = p&31;
        const float4* A = (const float4*)(sa + li*128);
        const float4* B = (const float4*)(sb + lj*128);
        float acc=0.f;
        #pragma unroll 8
        for(int i=0;i<32;i++){
            float4 a=A[i], b=B[i];
            acc += a.x*b.x + a.y*b.y + a.z*b.z + a.w*b.w;
        }
        float dd = fmaxf(sq[i0+li] + sq[j0+lj] - 2.f*acc, 0.f);
        d2[(size_t)(i0+li)*1024 + j0+lj] = dd;
        lm = fmaxf(lm, dd);
    }
    lm = block_max_f(lm,sred,4);
    if(tid==0) atomicMax(maxbits, __float_as_uint(lm));
}

// ---------------- out = 1 - sqrt(d2+eps)/maxd
__global__ __launch_bounds__(256) void k_final(
    const float* __restrict__ d2, const unsigned int* __restrict__ maxbits, float* __restrict__ out)
{
    int idx = blockIdx.x*256 + threadIdx.x;
    float md = sqrtf(__uint_as_float(*maxbits) + 1e-12f);
    out[idx] = 1.f - sqrtf(d2[idx] + 1e-12f)/md;
}

extern "C" void kernel_launch(void* const* d_in, const int* in_sizes, int n_in,
                              void* d_out, int out_size, void* d_ws, size_t ws_size,
                              hipStream_t stream)
{
    const float* x   = (const float*)d_in[0];
    const float* c1w = (const float*)d_in[1];  const float* c1b = (const float*)d_in[2];
    const float* g1g = (const float*)d_in[3];  const float* g1b = (const float*)d_in[4];
    const float* c2w = (const float*)d_in[5];  const float* c2b = (const float*)d_in[6];
    const float* g2g = (const float*)d_in[7];  const float* g2b = (const float*)d_in[8];
    const float* c3w = (const float*)d_in[9];  const float* c3b = (const float*)d_in[10];
    const float* g3g = (const float*)d_in[11]; const float* g3b = (const float*)d_in[12];
    const float* f1w = (const float*)d_in[13]; const float* f1b = (const float*)d_in[14];
    const float* wq  = (const float*)d_in[15]; const float* bq  = (const float*)d_in[16];
    const float* wk  = (const float*)d_in[17]; const float* bk  = (const float*)d_in[18];
    const float* wv  = (const float*)d_in[19]; const float* bv  = (const float*)d_in[20];

    float* W = (float*)d_ws;
    // Region A (aliases buf1, which is dead by then):
    float* e0   = W;                 // 1,048,576
    float* attn = W + 1048576;       // 1,048,576
    float* avb  = W + 2097152;       //   131,072
    float* eab  = W + 2228224;       //   131,072
    float* d2b  = W + 2359296;       // 1,048,576
    float* buf1 = W;                 // 18,874,368 (stage1 out, dead after k_conv2)
    float* buf2 = W + 18874368;      //  3,145,728 (stage2 out)
    float* wt   = W + 22020096;      //   131,072 (fc1_w transposed)
    float* wqt  = W + 22151168;      //    16,384
    float* wkt  = W + 22167552;      //    16,384
    float* wvt  = W + 22183936;      //    16,384
    float* eb   = W + 22200320;      //   131,072
    float* qb   = W + 22331392;      //   131,072
    float* kpb  = W + 22462464;      //   131,072
    float* vb   = W + 22593536;      //   131,072
    float* sqb  = W + 22724608;      //     1,024
    unsigned int* maxb = (unsigned int*)(W + 22725632);

    k_transpose<<<512,256,0,stream>>>(f1w, wt, 128, 1024);
    k_transpose<<<64,256,0,stream>>>(wq, wqt, 128, 128);
    k_transpose<<<64,256,0,stream>>>(wk, wkt, 128, 128);
    k_transpose<<<64,256,0,stream>>>(wv, wvt, 128, 128);

    k_conv1<<<dim3(4,1024),256,0,stream>>>(x,   c1w,c1b,g1g,g1b, buf1);
    k_conv2<<<1024,256,0,stream>>>(buf1,c2w,c2b,g2g,g2b, buf2);
    k_conv3<<<256,256,0,stream>>>(buf2,c3w,c3b,g3g,g3b, e0);

    k_fc1<<<1024,128,0,stream>>>(e0, wt, f1b, eb);
    k_qkv<<<1024,128,0,stream>>>(eb, wqt,bq, wkt,bk, wvt,bv, qb,kpb,vb);
    k_attn<<<1024,256,0,stream>>>(qb, kpb, attn);
    k_av<<<1024,128,0,stream>>>(attn, vb, avb);

    hipMemsetAsync(maxb, 0, 4, stream);
    k_colpipe<<<128,256,0,stream>>>(avb, eb, eab);
    k_sq<<<1024,128,0,stream>>>(eab, sqb);
    k_gram<<<dim3(32,32),256,0,stream>>>(eab, sqb, d2b, maxb);
    k_final<<<4096,256,0,stream>>>(d2b, maxb, (float*)d_out);
}